// Round 6
// baseline (22184.148 us; speedup 1.0000x reference)
//
#include <hip/hip_runtime.h>
#include <cstdint>
#include <cstddef>

// Problem constants
#define Bb   128
#define Tt   500
#define INn  306
#define Hh   512
#define GRID 128
#define BH   (Bb * Hh)              // 65536 elems per h slot

typedef short bf16x8 __attribute__((ext_vector_type(8)));
typedef float f32x4  __attribute__((ext_vector_type(4)));
typedef unsigned short u16t;

union F8 { bf16x8 v; uint4 q; unsigned u[4]; u16t s[8]; };

__device__ __forceinline__ float bf2f(u16t h) {
  unsigned u = ((unsigned)h) << 16;
  return __builtin_bit_cast(float, u);
}
__device__ __forceinline__ u16t f2bf(float f) {
  unsigned u = __builtin_bit_cast(unsigned, f);
  unsigned r = u + 0x7fffu + ((u >> 16) & 1u);   // RNE (finite inputs only)
  return (u16t)(r >> 16);
}
// hi+lo double-bf16 split, RNE (weights / h epilogue)
__device__ __forceinline__ void splitRNE(float v, u16t& hi, u16t& lo) {
  hi = f2bf(v);
  lo = f2bf(v - bf2f(hi));
}
// truncation split (per-step x conversion; pair residual ~2^-17 rel)
__device__ __forceinline__ void splitTR(float v, u16t& hi, u16t& lo) {
  unsigned u = __builtin_bit_cast(unsigned, v);
  hi = (u16t)(u >> 16);
  float hf = __builtin_bit_cast(float, u & 0xFFFF0000u);
  lo = (u16t)(__builtin_bit_cast(unsigned, v - hf) >> 16);
}
__device__ __forceinline__ f32x4 MF(const F8& a, const F8& b, f32x4 c) {
  return __builtin_amdgcn_mfma_f32_16x16x32_bf16(a.v, b.v, c, 0, 0, 0);
}

// Monotonic-counter grid barrier; every WG calls it the same number of times.
// Protocol empirically validated (R2/R3 ran 502 barriers to completion).
__device__ __forceinline__ void gbar(unsigned* ctr, unsigned& n) {
  n += GRID;
  __threadfence();          // release: make this WG's writes agent-visible
  __syncthreads();
  if (threadIdx.x == 0) {
    __hip_atomic_fetch_add(ctr, 1u, __ATOMIC_RELEASE, __HIP_MEMORY_SCOPE_AGENT);
    while (__hip_atomic_load(ctr, __ATOMIC_ACQUIRE, __HIP_MEMORY_SCOPE_AGENT) < n)
      __builtin_amdgcn_s_sleep(1);
  }
  __syncthreads();
  __threadfence();          // acquire side: discard stale cached h before reads
}

__global__ void bar_init(unsigned* ctr) { *ctr = 0u; }

__global__ __launch_bounds__(256, 1) void rnn_all(
    const float* x,
    const float* Wih0, const float* Whh0, const float* bih0, const float* bhh0,
    const float* Wih1, const float* Whh1, const float* bih1, const float* bhh1,
    const float* Wfc,  const float* bfc,
    float* out, unsigned char* ws)
{
  unsigned* bar = (unsigned*)ws;
  u16t* h0hi = (u16t*)(ws + 256);      // 4 arrays x 2 slots x 128x512 u16 = 1 MiB
  u16t* h0lo = h0hi + 2 * BH;
  u16t* h1hi = h0lo + 2 * BH;
  u16t* h1lo = h1hi + 2 * BH;

  const int wg   = blockIdx.x;
  const int tid  = threadIdx.x;
  const int lane = tid & 63;
  const int wave = tid >> 6;
  const int l15  = lane & 15;
  const int quad = lane >> 4;
  unsigned barn = 0;

  // Zero all h slots (ws is re-poisoned 0xAA each launch): 65536 uint4.
  {
    uint4 z; z.x = z.y = z.z = z.w = 0u;
    uint4* p = (uint4*)h0hi;
    const int gt = wg * 256 + tid;      // [0, 32768)
    p[gt] = z;
    p[gt + 32768] = z;
  }

  // Tiling: 64 WGs per layer; WG tile = 16 rows x 64 cols; 1 MFMA col-frag/wave.
  const bool isL0 = (wg < 64);
  const int id    = wg & 63;
  const int Mb    = (id >> 3) * 16;           // batch-row slice (8 slices)
  const int Jb    = (id & 7) * 64;            // col slice (8 slices)
  const int jn    = Jb + wave * 16 + l15;     // this lane's B-row / output col
  const int rowA  = Mb + l15;                 // A-row this lane loads
  const int mOutB = Mb + quad * 4;            // C/D: row = quad*4 + r

  if (isL0) {
    // ---------------- Layer 0 ----------------
    // Stationary hi/lo B fragments: W_ih0 (K=306 pad 320) + W_hh0 (K=512)
    // 52 F8 = 208 VGPR stationary.
    F8 Bxh[10], Bxl[10], Bhh[16], Bhl[16];
#pragma unroll
    for (int kc = 0; kc < 10; ++kc) {
#pragma unroll
      for (int e = 0; e < 8; ++e) {
        const int k = kc * 32 + quad * 8 + e;
        float v = (k < INn) ? Wih0[(size_t)jn * INn + k] : 0.f;
        splitRNE(v, Bxh[kc].s[e], Bxl[kc].s[e]);
      }
    }
#pragma unroll
    for (int kc = 0; kc < 16; ++kc) {
      const float* wr = Whh0 + (size_t)jn * Hh + kc * 32 + quad * 8;
#pragma unroll
      for (int e = 0; e < 8; ++e)
        splitRNE(wr[e], Bhh[kc].s[e], Bhl[kc].s[e]);
    }
    const float bv = bih0[jn] + bhh0[jn];

    auto step0 = [&](int t) {
      // x fragment for this step (f32 -> hi/lo bf16, in registers)
      F8 xh[10], xl[10];
      {
        const float* xr = x + ((size_t)rowA * Tt + t) * INn;  // 8B-aligned
#pragma unroll
        for (int kc = 0; kc < 10; ++kc) {
          const int kb = kc * 32 + quad * 8;
          float v[8];
          if (kc < 9) {
            const float2* p = (const float2*)(xr + kb);
#pragma unroll
            for (int h2 = 0; h2 < 4; ++h2) {
              float2 w = p[h2];
              v[2 * h2] = w.x; v[2 * h2 + 1] = w.y;
            }
          } else {
#pragma unroll
            for (int e = 0; e < 8; ++e)
              v[e] = (kb + e < INn) ? xr[kb + e] : 0.f;  // no OOB reads
          }
#pragma unroll
          for (int e = 0; e < 8; ++e) splitTR(v[e], xh[kc].s[e], xl[kc].s[e]);
        }
      }
      const int ps = (t + 1) & 1, cs = t & 1;
      const u16t* phi = h0hi + (size_t)ps * BH + (size_t)rowA * Hh + quad * 8;
      const u16t* plo = h0lo + (size_t)ps * BH + (size_t)rowA * Hh + quad * 8;
      f32x4 ac0 = {bv, bv, bv, bv};        // hi*hi chain (+bias)
      f32x4 ac1 = {0.f, 0.f, 0.f, 0.f};    // hi_a*lo_w chain
      f32x4 ac2 = {0.f, 0.f, 0.f, 0.f};    // lo_a*hi_w chain
#pragma unroll
      for (int kc = 0; kc < 16; ++kc) {
        F8 ah; ah.q = *(const uint4*)(phi + kc * 32);
        F8 al; al.q = *(const uint4*)(plo + kc * 32);
        ac0 = MF(ah, Bhh[kc], ac0);
        ac1 = MF(ah, Bhl[kc], ac1);
        ac2 = MF(al, Bhh[kc], ac2);
      }
#pragma unroll
      for (int kc = 0; kc < 10; ++kc) {
        ac0 = MF(xh[kc], Bxh[kc], ac0);
        ac1 = MF(xh[kc], Bxl[kc], ac1);
        ac2 = MF(xl[kc], Bxh[kc], ac2);
      }
      u16t* shi = h0hi + (size_t)cs * BH;
      u16t* slo = h0lo + (size_t)cs * BH;
#pragma unroll
      for (int r = 0; r < 4; ++r) {
        const float v = tanhf(ac0[r] + ac1[r] + ac2[r]);
        u16t hb, lb; splitRNE(v, hb, lb);
        const size_t m = (size_t)(mOutB + r) * Hh;
        shi[m + jn] = hb; slo[m + jn] = lb;
      }
    };

    // Barrier schedule: B0 | step0(t); B(t+1) for t=0..499 | B501
    gbar(bar, barn);                              // B0 (h zero visible)
    for (int t = 0; t < Tt; ++t) { step0(t); gbar(bar, barn); }  // B1..B500
    gbar(bar, barn);                              // B501 (h1[499] visible)

    // ---- FC + softmax (WG 0 only). OUTPUT IS FLOAT32 (ref: f32 softmax). ----
    if (wg == 0 && tid < Bb) {
      const int b = tid;
      const u16t* hh = h1hi + (size_t)((Tt - 1) & 1) * BH + (size_t)b * Hh;
      const u16t* hl = h1lo + (size_t)((Tt - 1) & 1) * BH + (size_t)b * Hh;
      float acc[4] = {bfc[0], bfc[1], bfc[2], bfc[3]};
      for (int j = 0; j < Hh; ++j) {
        const float hv = bf2f(hh[j]) + bf2f(hl[j]);
#pragma unroll
        for (int cc = 0; cc < 4; ++cc) acc[cc] += hv * Wfc[cc * Hh + j];
      }
      const float mx = fmaxf(fmaxf(acc[0], acc[1]), fmaxf(acc[2], acc[3]));
      const float e0 = expf(acc[0] - mx), e1 = expf(acc[1] - mx);
      const float e2 = expf(acc[2] - mx), e3 = expf(acc[3] - mx);
      const float si = 1.f / (e0 + e1 + e2 + e3);
      out[b * 4 + 0] = e0 * si;
      out[b * 4 + 1] = e1 * si;
      out[b * 4 + 2] = e2 * si;
      out[b * 4 + 3] = e3 * si;
    }
  } else {
    // ---------------- Layer 1 ----------------
    // Stationary hi/lo: W_ih1 + W_hh1, K=512 each. 64 F8 = 256 VGPR.
    F8 Bih[16], Bil[16], Bh2[16], Bl2[16];
#pragma unroll
    for (int kc = 0; kc < 16; ++kc) {
      const float* w1 = Wih1 + (size_t)jn * Hh + kc * 32 + quad * 8;
      const float* w2 = Whh1 + (size_t)jn * Hh + kc * 32 + quad * 8;
#pragma unroll
      for (int e = 0; e < 8; ++e) {
        splitRNE(w1[e], Bih[kc].s[e], Bil[kc].s[e]);
        splitRNE(w2[e], Bh2[kc].s[e], Bl2[kc].s[e]);
      }
    }
    const float bv = bih1[jn] + bhh1[jn];

    auto step1 = [&](int t1) {
      const int s0  = t1 & 1;          // h0[t1] slot (read)
      const int s1r = (t1 + 1) & 1;    // h1[t1-1] slot (read)
      const u16t* p0h = h0hi + (size_t)s0  * BH + (size_t)rowA * Hh + quad * 8;
      const u16t* p0l = h0lo + (size_t)s0  * BH + (size_t)rowA * Hh + quad * 8;
      const u16t* p1h = h1hi + (size_t)s1r * BH + (size_t)rowA * Hh + quad * 8;
      const u16t* p1l = h1lo + (size_t)s1r * BH + (size_t)rowA * Hh + quad * 8;
      f32x4 ac0 = {bv, bv, bv, bv};
      f32x4 ac1 = {0.f, 0.f, 0.f, 0.f};
      f32x4 ac2 = {0.f, 0.f, 0.f, 0.f};
#pragma unroll
      for (int kc = 0; kc < 16; ++kc) {
        F8 ah; ah.q = *(const uint4*)(p0h + kc * 32);
        F8 al; al.q = *(const uint4*)(p0l + kc * 32);
        ac0 = MF(ah, Bih[kc], ac0);
        ac1 = MF(ah, Bil[kc], ac1);
        ac2 = MF(al, Bih[kc], ac2);
      }
#pragma unroll
      for (int kc = 0; kc < 16; ++kc) {
        F8 ah; ah.q = *(const uint4*)(p1h + kc * 32);
        F8 al; al.q = *(const uint4*)(p1l + kc * 32);
        ac0 = MF(ah, Bh2[kc], ac0);
        ac1 = MF(ah, Bl2[kc], ac1);
        ac2 = MF(al, Bh2[kc], ac2);
      }
      u16t* shi = h1hi + (size_t)(t1 & 1) * BH;
      u16t* slo = h1lo + (size_t)(t1 & 1) * BH;
#pragma unroll
      for (int r = 0; r < 4; ++r) {
        const float v = tanhf(ac0[r] + ac1[r] + ac2[r]);
        u16t hb, lb; splitRNE(v, hb, lb);
        const size_t m = (size_t)(mOutB + r) * Hh;
        shi[m + jn] = hb; slo[m + jn] = lb;
      }
    };

    // Schedule: B0 | B1 | step1(t); B(t+2) for t=0..498 | step1(499); B501
    gbar(bar, barn);                              // B0
    gbar(bar, barn);                              // B1: h0[0] published
    for (int t = 0; t < Tt - 1; ++t) { step1(t); gbar(bar, barn); }  // B2..B500
    step1(Tt - 1);
    gbar(bar, barn);                              // B501
  }
}

extern "C" void kernel_launch(void* const* d_in, const int* in_sizes, int n_in,
                              void* d_out, int out_size, void* d_ws, size_t ws_size,
                              hipStream_t stream) {
  const float* x    = (const float*)d_in[0];
  const float* Wih0 = (const float*)d_in[1];
  const float* Whh0 = (const float*)d_in[2];
  const float* bih0 = (const float*)d_in[3];
  const float* bhh0 = (const float*)d_in[4];
  const float* Wih1 = (const float*)d_in[5];
  const float* Whh1 = (const float*)d_in[6];
  const float* bih1 = (const float*)d_in[7];
  const float* bhh1 = (const float*)d_in[8];
  const float* Wfc  = (const float*)d_in[9];
  const float* bfc  = (const float*)d_in[10];
  float* out = (float*)d_out;            // reference output dtype: float32
  unsigned char* ws = (unsigned char*)d_ws;

  bar_init<<<1, 1, 0, stream>>>((unsigned*)ws);
  // Plain launch: 128 WGs <= 256 CUs, sole resident kernel => co-residency
  // holds (empirically: R2/R3 completed their full 502-barrier protocols).
  rnn_all<<<dim3(GRID), dim3(256), 0, stream>>>(
      x, Wih0, Whh0, bih0, bhh0, Wih1, Whh1, bih1, bhh1, Wfc, bfc, out, ws);
}

// Round 8
// 8265.192 us; speedup vs baseline: 2.6840x; 2.6840x over previous
//
#include <hip/hip_runtime.h>
#include <cstdint>
#include <cstddef>

// Problem constants
#define Bb   128
#define Tt   500
#define INn  306
#define Hh   512
#define GRID 128
#define BH   (Bb * Hh)              // 65536 u16 per h slot

typedef short bf16x8 __attribute__((ext_vector_type(8)));
typedef float f32x4  __attribute__((ext_vector_type(4)));
typedef unsigned short u16t;

union F8 { bf16x8 v; uint4 q; unsigned u[4]; u16t s[8]; };

__device__ __forceinline__ float bf2f(u16t h) {
  unsigned u = ((unsigned)h) << 16;
  return __builtin_bit_cast(float, u);
}
__device__ __forceinline__ u16t f2bf(float f) {
  unsigned u = __builtin_bit_cast(unsigned, f);
  unsigned r = u + 0x7fffu + ((u >> 16) & 1u);   // RNE (finite inputs only)
  return (u16t)(r >> 16);
}
__device__ __forceinline__ void splitRNE(float v, u16t& hi, u16t& lo) {
  hi = f2bf(v);
  lo = f2bf(v - bf2f(hi));
}
__device__ __forceinline__ void splitTR(float v, u16t& hi, u16t& lo) {
  unsigned u = __builtin_bit_cast(unsigned, v);
  hi = (u16t)(u >> 16);
  float hf = __builtin_bit_cast(float, u & 0xFFFF0000u);
  lo = (u16t)(__builtin_bit_cast(unsigned, v - hf) >> 16);
}
__device__ __forceinline__ f32x4 MF(const F8& a, const F8& b, f32x4 c) {
  return __builtin_amdgcn_mfma_f32_16x16x32_bf16(a.v, b.v, c, 0, 0, 0);
}

// Coherent agent-scope store: compiler emits global_store_short ... sc1
// (write-through past the non-coherent per-XCD L2, visible after peers'
// buffer_inv). Counts toward vmcnt, so s_waitcnt vmcnt(0) drains it.
__device__ __forceinline__ void stsh(u16t* p, u16t v) {
  __hip_atomic_store(p, v, __ATOMIC_RELAXED, __HIP_MEMORY_SCOPE_AGENT);
}
__device__ __forceinline__ void stw(unsigned* p, unsigned v) {
  __hip_atomic_store(p, v, __ATOMIC_RELAXED, __HIP_MEMORY_SCOPE_AGENT);
}

// Group-local barrier: 16 WGs (sub 0 = leader). No atomic RMW, no threadfence.
// Release: vmcnt drain (sc1 stores ack at coherence point) + relaxed flag
// store. Acquire: buffer_inv sc1 (invalidate stale L1/L2 lines) after go.
__device__ __forceinline__ void gbar(unsigned* flags, unsigned* go,
                                     int sub, int tid, unsigned& s) {
  ++s;
  asm volatile("s_waitcnt vmcnt(0)" ::: "memory");   // drain this thread's stores
  __syncthreads();
  if (sub == 0) {
    if (tid >= 1 && tid < 16) {
      while (__hip_atomic_load(&flags[tid], __ATOMIC_RELAXED,
                               __HIP_MEMORY_SCOPE_AGENT) != s)
        __builtin_amdgcn_s_sleep(1);
    }
    __syncthreads();
    if (tid == 0)
      __hip_atomic_store(go, s, __ATOMIC_RELAXED, __HIP_MEMORY_SCOPE_AGENT);
  } else {
    if (tid == 0) {
      __hip_atomic_store(&flags[sub], s, __ATOMIC_RELAXED,
                         __HIP_MEMORY_SCOPE_AGENT);
      while (__hip_atomic_load(go, __ATOMIC_RELAXED,
                               __HIP_MEMORY_SCOPE_AGENT) != s)
        __builtin_amdgcn_s_sleep(1);
    }
    __syncthreads();
  }
  asm volatile("buffer_inv sc1" ::: "memory");       // acquire: drop stale h lines
}

__global__ __launch_bounds__(256, 1) void rnn_all(
    const float* x,
    const float* Wih0, const float* Whh0, const float* bih0, const float* bhh0,
    const float* Wih1, const float* Whh1, const float* bih1, const float* bhh1,
    const float* Wfc,  const float* bfc,
    float* out, unsigned char* ws)
{
  const int wg   = blockIdx.x;
  const int g    = wg >> 4;            // row-group 0..7 (16 batch rows each)
  const int sub  = wg & 15;            // 0..7 = L0 col-slices, 8..15 = L1
  const int tid  = threadIdx.x;
  const int lane = tid & 63;
  const int wave = tid >> 6;
  const int l15  = lane & 15;
  const int quad = lane >> 4;

  unsigned* flags = (unsigned*)(ws + (size_t)g * 128);       // 16 u32
  unsigned* go    = flags + 16;                              // same 128B block
  u16t* hbase = (u16t*)(ws + 1024);
  u16t* h0hi = hbase;                  // [2 slots][128][512] each plane
  u16t* h0lo = hbase + 2 * BH;
  u16t* h1hi = hbase + 4 * BH;
  u16t* h1lo = hbase + 6 * BH;
  unsigned s = 0;

  // Zero THIS GROUP's h rows (all 4 planes x 2 slots) with coherent stores.
  // Poisoned flags/go need no init: equality-polling vs s=1..502 never matches.
  {
    const int tg  = sub * 256 + tid;        // 0..4095
    const int reg = tg >> 9;                // 0..7 = (plane<<1)|slot
    const int pos = tg & 511;               // 8-elem chunk index in 16x512 rows
    u16t* dst = hbase + (size_t)(reg >> 1) * 2 * BH + (size_t)(reg & 1) * BH
              + (size_t)g * 8192 + (size_t)pos * 8;
#pragma unroll
    for (int i = 0; i < 4; ++i) stw((unsigned*)dst + i, 0u);
  }

  // Tiling: rows = g*16..g*16+15; cols = 64 per WG (wave*16 within).
  const bool isL0 = (sub < 8);
  const int Mb    = g * 16;
  const int Jb    = (isL0 ? sub : sub - 8) * 64;
  const int jn    = Jb + wave * 16 + l15;     // output col / B-row
  const int rowA  = Mb + l15;                 // A-row this lane loads
  const int mOutB = Mb + quad * 4;            // C/D: row = quad*4 + r

  if (isL0) {
    // ---------------- Layer 0 ----------------
    F8 Bxh[10], Bxl[10], Bhh[16], Bhl[16];
#pragma unroll
    for (int kc = 0; kc < 10; ++kc) {
#pragma unroll
      for (int e = 0; e < 8; ++e) {
        const int k = kc * 32 + quad * 8 + e;
        float v = (k < INn) ? Wih0[(size_t)jn * INn + k] : 0.f;
        splitRNE(v, Bxh[kc].s[e], Bxl[kc].s[e]);
      }
    }
#pragma unroll
    for (int kc = 0; kc < 16; ++kc) {
      const float* wr = Whh0 + (size_t)jn * Hh + kc * 32 + quad * 8;
#pragma unroll
      for (int e = 0; e < 8; ++e)
        splitRNE(wr[e], Bhh[kc].s[e], Bhl[kc].s[e]);
    }
    const float bv = bih0[jn] + bhh0[jn];

    auto step0 = [&](int t) {
      F8 xh[10], xl[10];
      {
        const float* xr = x + ((size_t)rowA * Tt + t) * INn;  // 8B-aligned
#pragma unroll
        for (int kc = 0; kc < 10; ++kc) {
          const int kb = kc * 32 + quad * 8;
          float v[8];
          if (kc < 9) {
            const float2* p = (const float2*)(xr + kb);
#pragma unroll
            for (int h2 = 0; h2 < 4; ++h2) {
              float2 w = p[h2];
              v[2 * h2] = w.x; v[2 * h2 + 1] = w.y;
            }
          } else {
#pragma unroll
            for (int e = 0; e < 8; ++e)
              v[e] = (kb + e < INn) ? xr[kb + e] : 0.f;
          }
#pragma unroll
          for (int e = 0; e < 8; ++e) splitTR(v[e], xh[kc].s[e], xl[kc].s[e]);
        }
      }
      const int ps = (t + 1) & 1, cs = t & 1;
      const u16t* phi = h0hi + (size_t)ps * BH + (size_t)rowA * Hh + quad * 8;
      const u16t* plo = h0lo + (size_t)ps * BH + (size_t)rowA * Hh + quad * 8;
      f32x4 ac0 = {bv, bv, bv, bv};
      f32x4 ac1 = {0.f, 0.f, 0.f, 0.f};
      f32x4 ac2 = {0.f, 0.f, 0.f, 0.f};
#pragma unroll
      for (int kc = 0; kc < 16; ++kc) {
        F8 ah; ah.q = *(const uint4*)(phi + kc * 32);
        F8 al; al.q = *(const uint4*)(plo + kc * 32);
        ac0 = MF(ah, Bhh[kc], ac0);
        ac1 = MF(ah, Bhl[kc], ac1);
        ac2 = MF(al, Bhh[kc], ac2);
      }
#pragma unroll
      for (int kc = 0; kc < 10; ++kc) {
        ac0 = MF(xh[kc], Bxh[kc], ac0);
        ac1 = MF(xh[kc], Bxl[kc], ac1);
        ac2 = MF(xl[kc], Bxh[kc], ac2);
      }
      u16t* shi = h0hi + (size_t)cs * BH;
      u16t* slo = h0lo + (size_t)cs * BH;
#pragma unroll
      for (int r = 0; r < 4; ++r) {
        const float v = tanhf(ac0[r] + ac1[r] + ac2[r]);
        u16t hb, lb; splitRNE(v, hb, lb);
        const size_t m = (size_t)(mOutB + r) * Hh;
        stsh(shi + m + jn, hb);
        stsh(slo + m + jn, lb);
      }
    };

    gbar(flags, go, sub, tid, s);                               // s=1 (zero done)
    for (int t = 0; t < Tt; ++t) { step0(t); gbar(flags, go, sub, tid, s); }
    gbar(flags, go, sub, tid, s);                               // s=502
  } else {
    // ---------------- Layer 1 ----------------
    F8 Bih[16], Bil[16], Bh2[16], Bl2[16];
#pragma unroll
    for (int kc = 0; kc < 16; ++kc) {
      const float* w1 = Wih1 + (size_t)jn * Hh + kc * 32 + quad * 8;
      const float* w2 = Whh1 + (size_t)jn * Hh + kc * 32 + quad * 8;
#pragma unroll
      for (int e = 0; e < 8; ++e) {
        splitRNE(w1[e], Bih[kc].s[e], Bil[kc].s[e]);
        splitRNE(w2[e], Bh2[kc].s[e], Bl2[kc].s[e]);
      }
    }
    const float bv = bih1[jn] + bhh1[jn];

    auto step1 = [&](int t1) {
      const int s0  = t1 & 1;          // h0[t1] slot (read)
      const int s1r = (t1 + 1) & 1;    // h1[t1-1] slot (read)
      const u16t* p0h = h0hi + (size_t)s0  * BH + (size_t)rowA * Hh + quad * 8;
      const u16t* p0l = h0lo + (size_t)s0  * BH + (size_t)rowA * Hh + quad * 8;
      const u16t* p1h = h1hi + (size_t)s1r * BH + (size_t)rowA * Hh + quad * 8;
      const u16t* p1l = h1lo + (size_t)s1r * BH + (size_t)rowA * Hh + quad * 8;
      f32x4 ac0 = {bv, bv, bv, bv};
      f32x4 ac1 = {0.f, 0.f, 0.f, 0.f};
      f32x4 ac2 = {0.f, 0.f, 0.f, 0.f};
#pragma unroll
      for (int kc = 0; kc < 16; ++kc) {
        F8 ah; ah.q = *(const uint4*)(p0h + kc * 32);
        F8 al; al.q = *(const uint4*)(p0l + kc * 32);
        ac0 = MF(ah, Bih[kc], ac0);
        ac1 = MF(ah, Bil[kc], ac1);
        ac2 = MF(al, Bih[kc], ac2);
      }
#pragma unroll
      for (int kc = 0; kc < 16; ++kc) {
        F8 ah; ah.q = *(const uint4*)(p1h + kc * 32);
        F8 al; al.q = *(const uint4*)(p1l + kc * 32);
        ac0 = MF(ah, Bh2[kc], ac0);
        ac1 = MF(ah, Bl2[kc], ac1);
        ac2 = MF(al, Bh2[kc], ac2);
      }
      u16t* shi = h1hi + (size_t)(t1 & 1) * BH;
      u16t* slo = h1lo + (size_t)(t1 & 1) * BH;
#pragma unroll
      for (int r = 0; r < 4; ++r) {
        const float v = tanhf(ac0[r] + ac1[r] + ac2[r]);
        u16t hb, lb; splitRNE(v, hb, lb);
        const size_t m = (size_t)(mOutB + r) * Hh;
        stsh(shi + m + jn, hb);
        stsh(slo + m + jn, lb);
      }
    };

    gbar(flags, go, sub, tid, s);                               // s=1
    gbar(flags, go, sub, tid, s);                               // s=2: h0[0] ready
    for (int t = 0; t < Tt - 1; ++t) { step1(t); gbar(flags, go, sub, tid, s); }
    step1(Tt - 1);
    gbar(flags, go, sub, tid, s);                               // s=502

    // ---- FC + softmax for this group's 16 batch rows (sub==8 only).
    // After bar 502 + buffer_inv, h1[499] (slot 1) is visible. f32 output.
    if (sub == 8 && tid < 16) {
      const int b = Mb + tid;
      const u16t* hh = h1hi + (size_t)1 * BH + (size_t)b * Hh;
      const u16t* hl = h1lo + (size_t)1 * BH + (size_t)b * Hh;
      float acc[4] = {bfc[0], bfc[1], bfc[2], bfc[3]};
      for (int j = 0; j < Hh; ++j) {
        const float hv = bf2f(hh[j]) + bf2f(hl[j]);
#pragma unroll
        for (int cc = 0; cc < 4; ++cc) acc[cc] += hv * Wfc[cc * Hh + j];
      }
      const float mx = fmaxf(fmaxf(acc[0], acc[1]), fmaxf(acc[2], acc[3]));
      const float e0 = expf(acc[0] - mx), e1 = expf(acc[1] - mx);
      const float e2 = expf(acc[2] - mx), e3 = expf(acc[3] - mx);
      const float si = 1.f / (e0 + e1 + e2 + e3);
      out[b * 4 + 0] = e0 * si;
      out[b * 4 + 1] = e1 * si;
      out[b * 4 + 2] = e2 * si;
      out[b * 4 + 3] = e3 * si;
    }
  }
}

extern "C" void kernel_launch(void* const* d_in, const int* in_sizes, int n_in,
                              void* d_out, int out_size, void* d_ws, size_t ws_size,
                              hipStream_t stream) {
  const float* x    = (const float*)d_in[0];
  const float* Wih0 = (const float*)d_in[1];
  const float* Whh0 = (const float*)d_in[2];
  const float* bih0 = (const float*)d_in[3];
  const float* bhh0 = (const float*)d_in[4];
  const float* Wih1 = (const float*)d_in[5];
  const float* Whh1 = (const float*)d_in[6];
  const float* bih1 = (const float*)d_in[7];
  const float* bhh1 = (const float*)d_in[8];
  const float* Wfc  = (const float*)d_in[9];
  const float* bfc  = (const float*)d_in[10];
  float* out = (float*)d_out;
  unsigned char* ws = (unsigned char*)d_ws;

  rnn_all<<<dim3(GRID), dim3(256), 0, stream>>>(
      x, Wih0, Whh0, bih0, bhh0, Wih1, Whh1, bih1, bhh1, Wfc, bfc, out, ws);
}